// Round 8
// baseline (329.523 us; speedup 1.0000x reference)
//
#include <hip/hip_runtime.h>
#include <hip/hip_bf16.h>

#define NEG_SLOPE 0.2f
#define EPS 1e-16f

typedef short  bf16x8  __attribute__((ext_vector_type(8)));
typedef float  f32x4   __attribute__((ext_vector_type(4)));
typedef float  nfloat4 __attribute__((ext_vector_type(4)));

__device__ __forceinline__ float bf2f(unsigned short u) {
    union { unsigned int i; float f; } c; c.i = ((unsigned int)u) << 16; return c.f;
}
__device__ __forceinline__ ushort f2bf(float f) {
    __hip_bfloat16 b = __float2bfloat16(f);
    return *(ushort*)&b;
}

// ---------------------------------------------------------------- CSR build
__global__ void hist_k(const int* __restrict__ dst, int E, int* __restrict__ deg) {
    int e = blockIdx.x * blockDim.x + threadIdx.x;
    if (e < E) atomicAdd(&deg[dst[e]], 1);
}

__global__ __launch_bounds__(1024) void scan1_k(const int* __restrict__ deg, int* __restrict__ offs,
                                                int* __restrict__ bsum, int n) {
    __shared__ int tmp[1024];
    int t = threadIdx.x;
    int i = blockIdx.x * 1024 + t;
    int v = (i < n) ? deg[i] : 0;
    tmp[t] = v;
    __syncthreads();
    int run = v;
    for (int off = 1; off < 1024; off <<= 1) {
        int add = (t >= off) ? tmp[t - off] : 0;
        __syncthreads();
        run += add;
        tmp[t] = run;
        __syncthreads();
    }
    if (i < n) offs[i] = run - v;
    if (t == 1023) bsum[blockIdx.x] = run;
}

// scan3 with in-wave block-prefix (requires nb <= 64)
__global__ __launch_bounds__(1024) void scan3_k(int* __restrict__ offs, const int* __restrict__ bsum,
                                                int n, int nb, int total) {
    int lane = threadIdx.x & 63;
    int v = (lane < nb && lane < (int)blockIdx.x) ? bsum[lane] : 0;
#pragma unroll
    for (int off = 32; off >= 1; off >>= 1) v += __shfl_xor(v, off);
    int i = blockIdx.x * 1024 + threadIdx.x;
    if (i < n) offs[i] += v;
    if (i == 0) offs[n] = total;
}

// ---------------- fill (dst-CSR) + wprep (W1aug/W2aug frag-order split-bf16), merged
#define NB_W1 (17 * 4 * 64 * 8)
#define NB_W2 (5 * 8 * 64 * 8)
__global__ void fill_wprep_k(const int* __restrict__ src, const int* __restrict__ dst, int E,
                             const int* __restrict__ offs, int* __restrict__ cur, int* __restrict__ csr,
                             int nbE,
                             const float* __restrict__ W1, const float* __restrict__ aS1,
                             const float* __restrict__ aD1, const float* __restrict__ W2,
                             const float* __restrict__ aS2, const float* __restrict__ aD2,
                             ushort* __restrict__ b1hi, ushort* __restrict__ b1lo,
                             ushort* __restrict__ b2hi, ushort* __restrict__ b2lo) {
    if ((int)blockIdx.x < nbE) {
        int e = blockIdx.x * blockDim.x + threadIdx.x;
        if (e >= E) return;
        int d = dst[e];
        int pos = offs[d] + atomicAdd(&cur[d], 1);
        csr[pos] = src[e];
        return;
    }
    int tid = (blockIdx.x - nbE) * blockDim.x + threadIdx.x;
    if (tid < NB_W1) {
        int j = tid & 7, lane = (tid >> 3) & 63, ks = (tid >> 9) & 3, nt = tid >> 11;
        int k = ks * 32 + (lane >> 4) * 8 + j;
        int col = nt * 16 + (lane & 15);
        float v = 0.f;
        if (col < 256) v = W1[k * 256 + col];
        else if (col < 264) {
            int cc = col - 256, h = cc & 3;
            const float* att = (cc < 4) ? aS1 : aD1;
            float s = 0.f;
            for (int c = 0; c < 64; c++) s += W1[k * 256 + h * 64 + c] * att[h * 64 + c];
            v = s;
        }
        ushort hi = f2bf(v);
        int idx = ((nt * 4 + ks) * 64 + lane) * 8 + j;
        b1hi[idx] = hi; b1lo[idx] = f2bf(v - bf2f(hi));
    } else if (tid < NB_W1 + NB_W2) {
        int t2 = tid - NB_W1;
        int j = t2 & 7, lane = (t2 >> 3) & 63, ks = (t2 >> 9) & 7, nt = t2 >> 12;
        int k = ks * 32 + (lane >> 4) * 8 + j;
        int col = nt * 16 + (lane & 15);
        float v = 0.f;
        if (col < 64) v = W2[k * 64 + col];
        else if (col == 64) { float s = 0.f; for (int c = 0; c < 64; c++) s += W2[k * 64 + c] * aS2[c]; v = s; }
        else if (col == 65) { float s = 0.f; for (int c = 0; c < 64; c++) s += W2[k * 64 + c] * aD2[c]; v = s; }
        ushort hi = f2bf(v);
        int idx = ((nt * 8 + ks) * 64 + lane) * 8 + j;
        b2hi[idx] = hi; b2lo[idx] = f2bf(v - bf2f(hi));
    }
}

// ------------------------------- GEMM1 MFMA: [N,128]x[128,272] split-bf16
__global__ __launch_bounds__(256) void gemm1_mfma_k(const float* __restrict__ x,
                                                    const bf16x8* __restrict__ bhi, const bf16x8* __restrict__ blo,
                                                    ushort* __restrict__ h1b, float* __restrict__ as1,
                                                    float* __restrict__ ad1, int N) {
    __shared__ ushort hs[4][16][256];
    int wid = threadIdx.x >> 6, lane = threadIdx.x & 63;
    int m0 = (blockIdx.x * 4 + wid) * 16;
    if (m0 >= N) return;
    int row = lane & 15, grp = lane >> 4;
    int rr = (m0 + row < N) ? (m0 + row) : (N - 1);
    const float4* xrow = (const float4*)(x + (size_t)rr * 128);

    bf16x8 ah[4], al[4];
#pragma unroll
    for (int ks = 0; ks < 4; ks++) {
        float4 f0 = xrow[ks * 8 + grp * 2];
        float4 f1 = xrow[ks * 8 + grp * 2 + 1];
        float fv[8] = {f0.x, f0.y, f0.z, f0.w, f1.x, f1.y, f1.z, f1.w};
#pragma unroll
        for (int j = 0; j < 8; j++) {
            ushort hi = f2bf(fv[j]);
            ah[ks][j] = (short)hi;
            al[ks][j] = (short)f2bf(fv[j] - bf2f(hi));
        }
    }

    int rows = N - m0; if (rows > 16) rows = 16;
    for (int nt = 0; nt < 17; nt++) {
        f32x4 acc = {0.f, 0.f, 0.f, 0.f};
#pragma unroll
        for (int ks = 0; ks < 4; ks++) {
            bf16x8 bh = bhi[(nt * 4 + ks) * 64 + lane];
            bf16x8 bl = blo[(nt * 4 + ks) * 64 + lane];
            acc = __builtin_amdgcn_mfma_f32_16x16x32_bf16(ah[ks], bh, acc, 0, 0, 0);
            acc = __builtin_amdgcn_mfma_f32_16x16x32_bf16(al[ks], bh, acc, 0, 0, 0);
            acc = __builtin_amdgcn_mfma_f32_16x16x32_bf16(ah[ks], bl, acc, 0, 0, 0);
        }
        if (nt < 16) {
            int col = nt * 16 + row, head = col >> 6, c = col & 63;
#pragma unroll
            for (int r = 0; r < 4; r++) hs[wid][grp * 4 + r][c * 4 + head] = f2bf(acc[r]);
        } else if (row < 8) {
#pragma unroll
            for (int r = 0; r < 4; r++) {
                int node = m0 + grp * 4 + r;
                if (node < N) {
                    if (row < 4) as1[node * 4 + row] = acc[r];
                    else         ad1[node * 4 + (row - 4)] = acc[r];
                }
            }
        }
    }
    ushort4* dst = (ushort4*)h1b + (size_t)m0 * 64;
    const ushort4* s4 = (const ushort4*)&hs[wid][0][0];
    for (int i = lane; i < rows * 64; i += 64) dst[i] = s4[i];
}

// ------------------------------- GEMM2 MFMA: [N,256]x[256,80], A bf16, W split
__global__ __launch_bounds__(256) void gemm2_mfma_k(const ushort* __restrict__ h1e,
                                                    const bf16x8* __restrict__ bhi, const bf16x8* __restrict__ blo,
                                                    ushort* __restrict__ h2b, float* __restrict__ as2,
                                                    float* __restrict__ ad2, int N) {
    __shared__ ushort hs[4][16][64];
    int wid = threadIdx.x >> 6, lane = threadIdx.x & 63;
    int m0 = (blockIdx.x * 4 + wid) * 16;
    if (m0 >= N) return;
    int row = lane & 15, grp = lane >> 4;
    const bf16x8* a8 = (const bf16x8*)h1e;
    bf16x8 a[8];
    int rr = (m0 + row < N) ? (m0 + row) : (N - 1);
    size_t rb = (size_t)rr * 32 + grp;
#pragma unroll
    for (int ks = 0; ks < 8; ks++) a[ks] = a8[rb + ks * 4];

    int rows = N - m0; if (rows > 16) rows = 16;
    for (int nt = 0; nt < 5; nt++) {
        f32x4 acc = {0.f, 0.f, 0.f, 0.f};
#pragma unroll
        for (int ks = 0; ks < 8; ks++) {
            bf16x8 bh = bhi[(nt * 8 + ks) * 64 + lane];
            bf16x8 bl = blo[(nt * 8 + ks) * 64 + lane];
            acc = __builtin_amdgcn_mfma_f32_16x16x32_bf16(a[ks], bh, acc, 0, 0, 0);
            acc = __builtin_amdgcn_mfma_f32_16x16x32_bf16(a[ks], bl, acc, 0, 0, 0);
        }
        if (nt < 4) {
            int col = nt * 16 + row;
#pragma unroll
            for (int r = 0; r < 4; r++) hs[wid][grp * 4 + r][col] = f2bf(acc[r]);
        } else if (row < 2) {
#pragma unroll
            for (int r = 0; r < 4; r++) {
                int node = m0 + grp * 4 + r;
                if (node < N) {
                    if (row == 0) as2[node] = acc[r];
                    else          ad2[node] = acc[r];
                }
            }
        }
    }
    ushort4* dst = (ushort4*)h2b + (size_t)m0 * 16;
    const ushort4* s4 = (const ushort4*)&hs[wid][0][0];
    for (int i = lane; i < rows * 16; i += 64) dst[i] = s4[i];
}

// --------------------------- layer-1 softmax+aggregate (4 heads, bf16 msgs)
// Inner gather loop unrolled x8 for memory-level parallelism.
__global__ __launch_bounds__(256) void agg4_k(const ushort4* __restrict__ hb, const float4* __restrict__ asv,
                                              const float4* __restrict__ adv, const int* __restrict__ offs,
                                              const int* __restrict__ csr, const float* __restrict__ bias,
                                              ushort* __restrict__ out, int N) {
    int node = (int)(((size_t)blockIdx.x * blockDim.x + threadIdx.x) >> 6);
    int lane = threadIdx.x & 63;
    if (node >= N) return;
    int beg = offs[node], end = offs[node + 1];
    int total = end - beg + 1;
    float4 ad = adv[node];

    float den0 = 0.f, den1 = 0.f, den2 = 0.f, den3 = 0.f;
    float acc0 = 0.f, acc1 = 0.f, acc2 = 0.f, acc3 = 0.f;

    for (int base = 0; base < total; base += 64) {
        int i = base + lane;
        bool valid = i < total;
        int s = node;
        if (valid && i > 0) s = csr[beg + i - 1];
        float4 av = asv[s];
        float e0 = av.x + ad.x; e0 = e0 > 0.f ? e0 : NEG_SLOPE * e0;
        float e1 = av.y + ad.y; e1 = e1 > 0.f ? e1 : NEG_SLOPE * e1;
        float e2 = av.z + ad.z; e2 = e2 > 0.f ? e2 : NEG_SLOPE * e2;
        float e3 = av.w + ad.w; e3 = e3 > 0.f ? e3 : NEG_SLOPE * e3;
        float p0 = valid ? __expf(e0) : 0.f;
        float p1 = valid ? __expf(e1) : 0.f;
        float p2 = valid ? __expf(e2) : 0.f;
        float p3 = valid ? __expf(e3) : 0.f;
        float q0 = p0, q1 = p1, q2 = p2, q3 = p3;
#pragma unroll
        for (int off = 32; off >= 1; off >>= 1) {
            q0 += __shfl_xor(q0, off);
            q1 += __shfl_xor(q1, off);
            q2 += __shfl_xor(q2, off);
            q3 += __shfl_xor(q3, off);
        }
        den0 += q0; den1 += q1; den2 += q2; den3 += q3;

        int cn = total - base; if (cn > 64) cn = 64;
        int cn8 = (cn + 7) & ~7;
        for (int j = 0; j < cn8; j += 8) {
            int sj[8];
            ushort4 vv[8];
#pragma unroll
            for (int u = 0; u < 8; u++) sj[u] = __shfl(s, j + u);
#pragma unroll
            for (int u = 0; u < 8; u++) vv[u] = hb[(size_t)sj[u] * 64 + lane];
#pragma unroll
            for (int u = 0; u < 8; u++) {
                float w0 = __shfl(p0, j + u), w1 = __shfl(p1, j + u);
                float w2 = __shfl(p2, j + u), w3 = __shfl(p3, j + u);
                acc0 = fmaf(bf2f(vv[u].x), w0, acc0);
                acc1 = fmaf(bf2f(vv[u].y), w1, acc1);
                acc2 = fmaf(bf2f(vv[u].z), w2, acc2);
                acc3 = fmaf(bf2f(vv[u].w), w3, acc3);
            }
        }
    }

    ushort* op = out + (size_t)node * 256 + lane;
    float o;
    o = acc0 / (den0 + EPS) + bias[lane];        o = o > 0.f ? o : expm1f(o); op[0]   = f2bf(o);
    o = acc1 / (den1 + EPS) + bias[64 + lane];   o = o > 0.f ? o : expm1f(o); op[64]  = f2bf(o);
    o = acc2 / (den2 + EPS) + bias[128 + lane];  o = o > 0.f ? o : expm1f(o); op[128] = f2bf(o);
    o = acc3 / (den3 + EPS) + bias[192 + lane];  o = o > 0.f ? o : expm1f(o); op[192] = f2bf(o);
}

// --------------------------- layer-2 softmax+aggregate (1 head, bf16 in/out)
__global__ __launch_bounds__(256) void agg1_k(const ushort* __restrict__ h2b, const float* __restrict__ asv,
                                              const float* __restrict__ adv, const int* __restrict__ offs,
                                              const int* __restrict__ csr, const float* __restrict__ bias,
                                              ushort* __restrict__ out, int N) {
    int node = (int)(((size_t)blockIdx.x * blockDim.x + threadIdx.x) >> 6);
    int lane = threadIdx.x & 63;
    if (node >= N) return;
    int beg = offs[node], end = offs[node + 1];
    int total = end - beg + 1;
    float ad = adv[node];

    float den = 0.f, acc = 0.f;
    for (int base = 0; base < total; base += 64) {
        int i = base + lane;
        bool valid = i < total;
        int s = node;
        if (valid && i > 0) s = csr[beg + i - 1];
        float e = asv[s] + ad;
        e = e > 0.f ? e : NEG_SLOPE * e;
        float p = valid ? __expf(e) : 0.f;
        float q = p;
#pragma unroll
        for (int off = 32; off >= 1; off >>= 1) q += __shfl_xor(q, off);
        den += q;

        int cn = total - base; if (cn > 64) cn = 64;
        int cn8 = (cn + 7) & ~7;
        for (int j = 0; j < cn8; j += 8) {
            int sj[8];
            float hv[8];
#pragma unroll
            for (int u = 0; u < 8; u++) sj[u] = __shfl(s, j + u);
#pragma unroll
            for (int u = 0; u < 8; u++) hv[u] = bf2f(h2b[(size_t)sj[u] * 64 + lane]);
#pragma unroll
            for (int u = 0; u < 8; u++) acc = fmaf(hv[u], __shfl(p, j + u), acc);
        }
    }
    out[(size_t)node * 64 + lane] = f2bf(acc / (den + EPS) + bias[lane]);
}

// ------------------- final edge gather (grid-stride, bf16 reads, f32 NT writes)
__global__ __launch_bounds__(256) void gather_k(const ushort4* __restrict__ h2a16, const int* __restrict__ srcv,
                                                const int* __restrict__ dstv, nfloat4* __restrict__ out, int E) {
    int total = E * 32;
    int stride = gridDim.x * blockDim.x;
    for (int t = blockIdx.x * blockDim.x + threadIdx.x; t < total; t += stride) {
        int e = t >> 5, q = t & 31;
        int node = (q < 16) ? srcv[e] : dstv[e];
        ushort4 v = h2a16[(size_t)node * 16 + (q & 15)];
        nfloat4 f = {bf2f(v.x), bf2f(v.y), bf2f(v.z), bf2f(v.w)};
        __builtin_nontemporal_store(f, &out[t]);
    }
}

// ---------------------------------------------------------------- launcher
extern "C" void kernel_launch(void* const* d_in, const int* in_sizes, int n_in,
                              void* d_out, int out_size, void* d_ws, size_t ws_size,
                              hipStream_t stream) {
    const float* x   = (const float*)d_in[0];
    const int*   ei  = (const int*)d_in[1];
    const float* W1  = (const float*)d_in[2];
    const float* aS1 = (const float*)d_in[3];
    const float* aD1 = (const float*)d_in[4];
    const float* b1  = (const float*)d_in[5];
    const float* W2  = (const float*)d_in[6];
    const float* aS2 = (const float*)d_in[7];
    const float* aD2 = (const float*)d_in[8];
    const float* b2  = (const float*)d_in[9];
    float* out = (float*)d_out;

    int N = in_sizes[0] / 128;
    int E = in_sizes[1] / 2;
    const int* srcv = ei;
    const int* dstv = ei + E;

    size_t off = 0;
    char* base = (char*)d_ws;
    auto alloc = [&](size_t bytes) -> void* {
        void* p = base + off;
        off = (off + bytes + 255) & ~(size_t)255;
        return p;
    };
    int*    deg  = (int*)alloc((size_t)2 * N * 4);        // [deg|cur]
    int*    cur  = deg + N;
    int*    offs = (int*)alloc((size_t)(N + 1) * 4);
    int*    bsum = (int*)alloc(256 * 4);
    int*    csr  = (int*)alloc((size_t)E * 4);
    float*  as1  = (float*)alloc((size_t)N * 16);
    float*  ad1  = (float*)alloc((size_t)N * 16);
    float*  as2  = (float*)alloc((size_t)N * 4);
    float*  ad2  = (float*)alloc((size_t)N * 4);
    ushort* b1hi = (ushort*)alloc(NB_W1 * 2);
    ushort* b1lo = (ushort*)alloc(NB_W1 * 2);
    ushort* b2hi = (ushort*)alloc(NB_W2 * 2);
    ushort* b2lo = (ushort*)alloc(NB_W2 * 2);
    ushort* h1b  = (ushort*)alloc((size_t)N * 256 * 2);   // bf16 packed [node][c][head]
    ushort* h1e  = (ushort*)alloc((size_t)N * 256 * 2);   // bf16 [N][256] after ELU
    ushort* h2b  = h1b;                                    // aliases (h1b dead after agg4)
    ushort* h2a  = h1b + (size_t)N * 64;

    (void)hipMemsetAsync(deg, 0, (size_t)2 * N * 4, stream);

    int nbE = (E + 255) / 256;
    hist_k<<<nbE, 256, 0, stream>>>(dstv, E, deg);
    int nbS = (N + 1023) / 1024;
    scan1_k<<<nbS, 1024, 0, stream>>>(deg, offs, bsum, N);
    scan3_k<<<nbS, 1024, 0, stream>>>(offs, bsum, N, nbS, E);

    int nbW = (NB_W1 + NB_W2 + 255) / 256;
    fill_wprep_k<<<nbE + nbW, 256, 0, stream>>>(srcv, dstv, E, offs, cur, csr, nbE,
                                                W1, aS1, aD1, W2, aS2, aD2,
                                                b1hi, b1lo, b2hi, b2lo);

    int nstrip = (N + 15) / 16;
    int nbG1 = (nstrip + 3) / 4;
    gemm1_mfma_k<<<nbG1, 256, 0, stream>>>(x, (const bf16x8*)b1hi, (const bf16x8*)b1lo,
                                           h1b, as1, ad1, N);

    int nbA = (N * 64 + 255) / 256;
    agg4_k<<<nbA, 256, 0, stream>>>((const ushort4*)h1b, (const float4*)as1, (const float4*)ad1,
                                    offs, csr, b1, h1e, N);

    gemm2_mfma_k<<<nbG1, 256, 0, stream>>>(h1e, (const bf16x8*)b2hi, (const bf16x8*)b2lo,
                                           h2b, as2, ad2, N);

    agg1_k<<<nbA, 256, 0, stream>>>(h2b, as2, ad2, offs, csr, b2, h2a, N);

    gather_k<<<4096, 256, 0, stream>>>((const ushort4*)h2a, srcv, dstv, (nfloat4*)out, E);
}

// Round 9
// 312.156 us; speedup vs baseline: 1.0556x; 1.0556x over previous
//
#include <hip/hip_runtime.h>
#include <hip/hip_bf16.h>

#define NEG_SLOPE 0.2f
#define EPS 1e-16f

typedef short  bf16x8  __attribute__((ext_vector_type(8)));
typedef float  f32x4   __attribute__((ext_vector_type(4)));
typedef float  nfloat4 __attribute__((ext_vector_type(4)));

__device__ __forceinline__ float bf2f(unsigned short u) {
    union { unsigned int i; float f; } c; c.i = ((unsigned int)u) << 16; return c.f;
}
__device__ __forceinline__ ushort f2bf(float f) {
    __hip_bfloat16 b = __float2bfloat16(f);
    return *(ushort*)&b;
}

// ---------------------------------------------------------------- CSR build
__global__ void hist_k(const int* __restrict__ dst, int E, int* __restrict__ deg) {
    int e = blockIdx.x * blockDim.x + threadIdx.x;
    if (e < E) atomicAdd(&deg[dst[e]], 1);
}

__global__ __launch_bounds__(1024) void scan1_k(const int* __restrict__ deg, int* __restrict__ offs,
                                                int* __restrict__ bsum, int n) {
    __shared__ int tmp[1024];
    int t = threadIdx.x;
    int i = blockIdx.x * 1024 + t;
    int v = (i < n) ? deg[i] : 0;
    tmp[t] = v;
    __syncthreads();
    int run = v;
    for (int off = 1; off < 1024; off <<= 1) {
        int add = (t >= off) ? tmp[t - off] : 0;
        __syncthreads();
        run += add;
        tmp[t] = run;
        __syncthreads();
    }
    if (i < n) offs[i] = run - v;
    if (t == 1023) bsum[blockIdx.x] = run;
}

// scan3 with in-wave block-prefix (requires nb <= 64)
__global__ __launch_bounds__(1024) void scan3_k(int* __restrict__ offs, const int* __restrict__ bsum,
                                                int n, int nb, int total) {
    int lane = threadIdx.x & 63;
    int v = (lane < nb && lane < (int)blockIdx.x) ? bsum[lane] : 0;
#pragma unroll
    for (int off = 32; off >= 1; off >>= 1) v += __shfl_xor(v, off);
    int i = blockIdx.x * 1024 + threadIdx.x;
    if (i < n) offs[i] += v;
    if (i == 0) offs[n] = total;
}

// ---------------- fill (dst-CSR) + wprep (W1aug/W2aug frag-order split-bf16), merged
#define NB_W1 (17 * 4 * 64 * 8)
#define NB_W2 (5 * 8 * 64 * 8)
__global__ void fill_wprep_k(const int* __restrict__ src, const int* __restrict__ dst, int E,
                             const int* __restrict__ offs, int* __restrict__ cur, int* __restrict__ csr,
                             int nbE,
                             const float* __restrict__ W1, const float* __restrict__ aS1,
                             const float* __restrict__ aD1, const float* __restrict__ W2,
                             const float* __restrict__ aS2, const float* __restrict__ aD2,
                             ushort* __restrict__ b1hi, ushort* __restrict__ b1lo,
                             ushort* __restrict__ b2hi, ushort* __restrict__ b2lo) {
    if ((int)blockIdx.x < nbE) {
        int e = blockIdx.x * blockDim.x + threadIdx.x;
        if (e >= E) return;
        int d = dst[e];
        int pos = offs[d] + atomicAdd(&cur[d], 1);
        csr[pos] = src[e];
        return;
    }
    int tid = (blockIdx.x - nbE) * blockDim.x + threadIdx.x;
    if (tid < NB_W1) {
        int j = tid & 7, lane = (tid >> 3) & 63, ks = (tid >> 9) & 3, nt = tid >> 11;
        int k = ks * 32 + (lane >> 4) * 8 + j;
        int col = nt * 16 + (lane & 15);
        float v = 0.f;
        if (col < 256) v = W1[k * 256 + col];
        else if (col < 264) {
            int cc = col - 256, h = cc & 3;
            const float* att = (cc < 4) ? aS1 : aD1;
            float s = 0.f;
            for (int c = 0; c < 64; c++) s += W1[k * 256 + h * 64 + c] * att[h * 64 + c];
            v = s;
        }
        ushort hi = f2bf(v);
        int idx = ((nt * 4 + ks) * 64 + lane) * 8 + j;
        b1hi[idx] = hi; b1lo[idx] = f2bf(v - bf2f(hi));
    } else if (tid < NB_W1 + NB_W2) {
        int t2 = tid - NB_W1;
        int j = t2 & 7, lane = (t2 >> 3) & 63, ks = (t2 >> 9) & 7, nt = t2 >> 12;
        int k = ks * 32 + (lane >> 4) * 8 + j;
        int col = nt * 16 + (lane & 15);
        float v = 0.f;
        if (col < 64) v = W2[k * 64 + col];
        else if (col == 64) { float s = 0.f; for (int c = 0; c < 64; c++) s += W2[k * 64 + c] * aS2[c]; v = s; }
        else if (col == 65) { float s = 0.f; for (int c = 0; c < 64; c++) s += W2[k * 64 + c] * aD2[c]; v = s; }
        ushort hi = f2bf(v);
        int idx = ((nt * 8 + ks) * 64 + lane) * 8 + j;
        b2hi[idx] = hi; b2lo[idx] = f2bf(v - bf2f(hi));
    }
}

// ------------------------------- GEMM1 MFMA: [N,128]x[128,272] split-bf16
__global__ __launch_bounds__(256) void gemm1_mfma_k(const float* __restrict__ x,
                                                    const bf16x8* __restrict__ bhi, const bf16x8* __restrict__ blo,
                                                    ushort* __restrict__ h1b, float* __restrict__ as1,
                                                    float* __restrict__ ad1, int N) {
    __shared__ ushort hs[4][16][256];
    int wid = threadIdx.x >> 6, lane = threadIdx.x & 63;
    int m0 = (blockIdx.x * 4 + wid) * 16;
    if (m0 >= N) return;
    int row = lane & 15, grp = lane >> 4;
    int rr = (m0 + row < N) ? (m0 + row) : (N - 1);
    const float4* xrow = (const float4*)(x + (size_t)rr * 128);

    bf16x8 ah[4], al[4];
#pragma unroll
    for (int ks = 0; ks < 4; ks++) {
        float4 f0 = xrow[ks * 8 + grp * 2];
        float4 f1 = xrow[ks * 8 + grp * 2 + 1];
        float fv[8] = {f0.x, f0.y, f0.z, f0.w, f1.x, f1.y, f1.z, f1.w};
#pragma unroll
        for (int j = 0; j < 8; j++) {
            ushort hi = f2bf(fv[j]);
            ah[ks][j] = (short)hi;
            al[ks][j] = (short)f2bf(fv[j] - bf2f(hi));
        }
    }

    int rows = N - m0; if (rows > 16) rows = 16;
    for (int nt = 0; nt < 17; nt++) {
        f32x4 acc = {0.f, 0.f, 0.f, 0.f};
#pragma unroll
        for (int ks = 0; ks < 4; ks++) {
            bf16x8 bh = bhi[(nt * 4 + ks) * 64 + lane];
            bf16x8 bl = blo[(nt * 4 + ks) * 64 + lane];
            acc = __builtin_amdgcn_mfma_f32_16x16x32_bf16(ah[ks], bh, acc, 0, 0, 0);
            acc = __builtin_amdgcn_mfma_f32_16x16x32_bf16(al[ks], bh, acc, 0, 0, 0);
            acc = __builtin_amdgcn_mfma_f32_16x16x32_bf16(ah[ks], bl, acc, 0, 0, 0);
        }
        if (nt < 16) {
            int col = nt * 16 + row, head = col >> 6, c = col & 63;
#pragma unroll
            for (int r = 0; r < 4; r++) hs[wid][grp * 4 + r][c * 4 + head] = f2bf(acc[r]);
        } else if (row < 8) {
#pragma unroll
            for (int r = 0; r < 4; r++) {
                int node = m0 + grp * 4 + r;
                if (node < N) {
                    if (row < 4) as1[node * 4 + row] = acc[r];
                    else         ad1[node * 4 + (row - 4)] = acc[r];
                }
            }
        }
    }
    ushort4* dst = (ushort4*)h1b + (size_t)m0 * 64;
    const ushort4* s4 = (const ushort4*)&hs[wid][0][0];
    for (int i = lane; i < rows * 64; i += 64) dst[i] = s4[i];
}

// ------------------------------- GEMM2 MFMA: [N,256]x[256,80], A bf16, W split
__global__ __launch_bounds__(256) void gemm2_mfma_k(const ushort* __restrict__ h1e,
                                                    const bf16x8* __restrict__ bhi, const bf16x8* __restrict__ blo,
                                                    ushort* __restrict__ h2b, float* __restrict__ as2,
                                                    float* __restrict__ ad2, int N) {
    __shared__ ushort hs[4][16][64];
    int wid = threadIdx.x >> 6, lane = threadIdx.x & 63;
    int m0 = (blockIdx.x * 4 + wid) * 16;
    if (m0 >= N) return;
    int row = lane & 15, grp = lane >> 4;
    const bf16x8* a8 = (const bf16x8*)h1e;
    bf16x8 a[8];
    int rr = (m0 + row < N) ? (m0 + row) : (N - 1);
    size_t rb = (size_t)rr * 32 + grp;
#pragma unroll
    for (int ks = 0; ks < 8; ks++) a[ks] = a8[rb + ks * 4];

    int rows = N - m0; if (rows > 16) rows = 16;
    for (int nt = 0; nt < 5; nt++) {
        f32x4 acc = {0.f, 0.f, 0.f, 0.f};
#pragma unroll
        for (int ks = 0; ks < 8; ks++) {
            bf16x8 bh = bhi[(nt * 8 + ks) * 64 + lane];
            bf16x8 bl = blo[(nt * 8 + ks) * 64 + lane];
            acc = __builtin_amdgcn_mfma_f32_16x16x32_bf16(a[ks], bh, acc, 0, 0, 0);
            acc = __builtin_amdgcn_mfma_f32_16x16x32_bf16(a[ks], bl, acc, 0, 0, 0);
        }
        if (nt < 4) {
            int col = nt * 16 + row;
#pragma unroll
            for (int r = 0; r < 4; r++) hs[wid][grp * 4 + r][col] = f2bf(acc[r]);
        } else if (row < 2) {
#pragma unroll
            for (int r = 0; r < 4; r++) {
                int node = m0 + grp * 4 + r;
                if (node < N) {
                    if (row == 0) as2[node] = acc[r];
                    else          ad2[node] = acc[r];
                }
            }
        }
    }
    ushort4* dst = (ushort4*)h2b + (size_t)m0 * 16;
    const ushort4* s4 = (const ushort4*)&hs[wid][0][0];
    for (int i = lane; i < rows * 16; i += 64) dst[i] = s4[i];
}

// --------------------------- layer-1 softmax+aggregate (4 heads, bf16 msgs)
__global__ __launch_bounds__(256) void agg4_k(const ushort4* __restrict__ hb, const float4* __restrict__ asv,
                                              const float4* __restrict__ adv, const int* __restrict__ offs,
                                              const int* __restrict__ csr, const float* __restrict__ bias,
                                              ushort* __restrict__ out, int N) {
    int node = (int)(((size_t)blockIdx.x * blockDim.x + threadIdx.x) >> 6);
    int lane = threadIdx.x & 63;
    if (node >= N) return;
    int beg = offs[node], end = offs[node + 1];
    int total = end - beg + 1;
    float4 ad = adv[node];

    float den0 = 0.f, den1 = 0.f, den2 = 0.f, den3 = 0.f;
    float acc0 = 0.f, acc1 = 0.f, acc2 = 0.f, acc3 = 0.f;

    for (int base = 0; base < total; base += 64) {
        int i = base + lane;
        bool valid = i < total;
        int s = node;
        if (valid && i > 0) s = csr[beg + i - 1];
        float4 av = asv[s];
        float e0 = av.x + ad.x; e0 = e0 > 0.f ? e0 : NEG_SLOPE * e0;
        float e1 = av.y + ad.y; e1 = e1 > 0.f ? e1 : NEG_SLOPE * e1;
        float e2 = av.z + ad.z; e2 = e2 > 0.f ? e2 : NEG_SLOPE * e2;
        float e3 = av.w + ad.w; e3 = e3 > 0.f ? e3 : NEG_SLOPE * e3;
        float p0 = valid ? __expf(e0) : 0.f;
        float p1 = valid ? __expf(e1) : 0.f;
        float p2 = valid ? __expf(e2) : 0.f;
        float p3 = valid ? __expf(e3) : 0.f;
        float q0 = p0, q1 = p1, q2 = p2, q3 = p3;
#pragma unroll
        for (int off = 32; off >= 1; off >>= 1) {
            q0 += __shfl_xor(q0, off);
            q1 += __shfl_xor(q1, off);
            q2 += __shfl_xor(q2, off);
            q3 += __shfl_xor(q3, off);
        }
        den0 += q0; den1 += q1; den2 += q2; den3 += q3;

        int cn = total - base; if (cn > 64) cn = 64;
        int cn4 = (cn + 3) & ~3;
        for (int j = 0; j < cn4; j += 4) {
            int s0 = __shfl(s, j), s1 = __shfl(s, j + 1), s2 = __shfl(s, j + 2), s3 = __shfl(s, j + 3);
            ushort4 v0 = hb[(size_t)s0 * 64 + lane];
            ushort4 v1 = hb[(size_t)s1 * 64 + lane];
            ushort4 v2 = hb[(size_t)s2 * 64 + lane];
            ushort4 v3 = hb[(size_t)s3 * 64 + lane];
            float w00 = __shfl(p0, j), w01 = __shfl(p1, j), w02 = __shfl(p2, j), w03 = __shfl(p3, j);
            acc0 = fmaf(bf2f(v0.x), w00, acc0);
            acc1 = fmaf(bf2f(v0.y), w01, acc1);
            acc2 = fmaf(bf2f(v0.z), w02, acc2);
            acc3 = fmaf(bf2f(v0.w), w03, acc3);
            float w10 = __shfl(p0, j + 1), w11 = __shfl(p1, j + 1), w12 = __shfl(p2, j + 1), w13 = __shfl(p3, j + 1);
            acc0 = fmaf(bf2f(v1.x), w10, acc0);
            acc1 = fmaf(bf2f(v1.y), w11, acc1);
            acc2 = fmaf(bf2f(v1.z), w12, acc2);
            acc3 = fmaf(bf2f(v1.w), w13, acc3);
            float w20 = __shfl(p0, j + 2), w21 = __shfl(p1, j + 2), w22 = __shfl(p2, j + 2), w23 = __shfl(p3, j + 2);
            acc0 = fmaf(bf2f(v2.x), w20, acc0);
            acc1 = fmaf(bf2f(v2.y), w21, acc1);
            acc2 = fmaf(bf2f(v2.z), w22, acc2);
            acc3 = fmaf(bf2f(v2.w), w23, acc3);
            float w30 = __shfl(p0, j + 3), w31 = __shfl(p1, j + 3), w32 = __shfl(p2, j + 3), w33 = __shfl(p3, j + 3);
            acc0 = fmaf(bf2f(v3.x), w30, acc0);
            acc1 = fmaf(bf2f(v3.y), w31, acc1);
            acc2 = fmaf(bf2f(v3.z), w32, acc2);
            acc3 = fmaf(bf2f(v3.w), w33, acc3);
        }
    }

    ushort* op = out + (size_t)node * 256 + lane;
    float o;
    o = acc0 / (den0 + EPS) + bias[lane];        o = o > 0.f ? o : expm1f(o); op[0]   = f2bf(o);
    o = acc1 / (den1 + EPS) + bias[64 + lane];   o = o > 0.f ? o : expm1f(o); op[64]  = f2bf(o);
    o = acc2 / (den2 + EPS) + bias[128 + lane];  o = o > 0.f ? o : expm1f(o); op[128] = f2bf(o);
    o = acc3 / (den3 + EPS) + bias[192 + lane];  o = o > 0.f ? o : expm1f(o); op[192] = f2bf(o);
}

// --------------------------- layer-2 softmax+aggregate (1 head, bf16 in/out)
__global__ __launch_bounds__(256) void agg1_k(const ushort* __restrict__ h2b, const float* __restrict__ asv,
                                              const float* __restrict__ adv, const int* __restrict__ offs,
                                              const int* __restrict__ csr, const float* __restrict__ bias,
                                              ushort* __restrict__ out, int N) {
    int node = (int)(((size_t)blockIdx.x * blockDim.x + threadIdx.x) >> 6);
    int lane = threadIdx.x & 63;
    if (node >= N) return;
    int beg = offs[node], end = offs[node + 1];
    int total = end - beg + 1;
    float ad = adv[node];

    float den = 0.f, acc = 0.f;
    for (int base = 0; base < total; base += 64) {
        int i = base + lane;
        bool valid = i < total;
        int s = node;
        if (valid && i > 0) s = csr[beg + i - 1];
        float e = asv[s] + ad;
        e = e > 0.f ? e : NEG_SLOPE * e;
        float p = valid ? __expf(e) : 0.f;
        float q = p;
#pragma unroll
        for (int off = 32; off >= 1; off >>= 1) q += __shfl_xor(q, off);
        den += q;

        int cn = total - base; if (cn > 64) cn = 64;
        int cn4 = (cn + 3) & ~3;
        for (int j = 0; j < cn4; j += 4) {
            int s0 = __shfl(s, j), s1 = __shfl(s, j + 1), s2 = __shfl(s, j + 2), s3 = __shfl(s, j + 3);
            float h0 = bf2f(h2b[(size_t)s0 * 64 + lane]);
            float h1 = bf2f(h2b[(size_t)s1 * 64 + lane]);
            float h2v = bf2f(h2b[(size_t)s2 * 64 + lane]);
            float h3 = bf2f(h2b[(size_t)s3 * 64 + lane]);
            acc = fmaf(h0, __shfl(p, j), acc);
            acc = fmaf(h1, __shfl(p, j + 1), acc);
            acc = fmaf(h2v, __shfl(p, j + 2), acc);
            acc = fmaf(h3, __shfl(p, j + 3), acc);
        }
    }
    out[(size_t)node * 64 + lane] = f2bf(acc / (den + EPS) + bias[lane]);
}

// ------------------------- final edge gather (bf16 reads, f32 coalesced NT writes)
__global__ void gather_k(const ushort4* __restrict__ h2a16, const int* __restrict__ srcv,
                         const int* __restrict__ dstv, nfloat4* __restrict__ out, int E) {
    int t = blockIdx.x * blockDim.x + threadIdx.x;
    if (t >= E * 32) return;
    int e = t >> 5, q = t & 31;
    int node = (q < 16) ? srcv[e] : dstv[e];
    ushort4 v = h2a16[(size_t)node * 16 + (q & 15)];
    nfloat4 f = {bf2f(v.x), bf2f(v.y), bf2f(v.z), bf2f(v.w)};
    __builtin_nontemporal_store(f, &out[t]);
}

// ---------------------------------------------------------------- launcher
extern "C" void kernel_launch(void* const* d_in, const int* in_sizes, int n_in,
                              void* d_out, int out_size, void* d_ws, size_t ws_size,
                              hipStream_t stream) {
    const float* x   = (const float*)d_in[0];
    const int*   ei  = (const int*)d_in[1];
    const float* W1  = (const float*)d_in[2];
    const float* aS1 = (const float*)d_in[3];
    const float* aD1 = (const float*)d_in[4];
    const float* b1  = (const float*)d_in[5];
    const float* W2  = (const float*)d_in[6];
    const float* aS2 = (const float*)d_in[7];
    const float* aD2 = (const float*)d_in[8];
    const float* b2  = (const float*)d_in[9];
    float* out = (float*)d_out;

    int N = in_sizes[0] / 128;
    int E = in_sizes[1] / 2;
    const int* srcv = ei;
    const int* dstv = ei + E;

    size_t off = 0;
    char* base = (char*)d_ws;
    auto alloc = [&](size_t bytes) -> void* {
        void* p = base + off;
        off = (off + bytes + 255) & ~(size_t)255;
        return p;
    };
    int*    deg  = (int*)alloc((size_t)2 * N * 4);        // [deg|cur]
    int*    cur  = deg + N;
    int*    offs = (int*)alloc((size_t)(N + 1) * 4);
    int*    bsum = (int*)alloc(256 * 4);
    int*    csr  = (int*)alloc((size_t)E * 4);
    float*  as1  = (float*)alloc((size_t)N * 16);
    float*  ad1  = (float*)alloc((size_t)N * 16);
    float*  as2  = (float*)alloc((size_t)N * 4);
    float*  ad2  = (float*)alloc((size_t)N * 4);
    ushort* b1hi = (ushort*)alloc(NB_W1 * 2);
    ushort* b1lo = (ushort*)alloc(NB_W1 * 2);
    ushort* b2hi = (ushort*)alloc(NB_W2 * 2);
    ushort* b2lo = (ushort*)alloc(NB_W2 * 2);
    ushort* h1b  = (ushort*)alloc((size_t)N * 256 * 2);   // bf16 packed [node][c][head]
    ushort* h1e  = (ushort*)alloc((size_t)N * 256 * 2);   // bf16 [N][256] after ELU
    ushort* h2b  = h1b;                                    // aliases (h1b dead after agg4)
    ushort* h2a  = h1b + (size_t)N * 64;

    (void)hipMemsetAsync(deg, 0, (size_t)2 * N * 4, stream);

    int nbE = (E + 255) / 256;
    hist_k<<<nbE, 256, 0, stream>>>(dstv, E, deg);
    int nbS = (N + 1023) / 1024;
    scan1_k<<<nbS, 1024, 0, stream>>>(deg, offs, bsum, N);
    scan3_k<<<nbS, 1024, 0, stream>>>(offs, bsum, N, nbS, E);

    int nbW = (NB_W1 + NB_W2 + 255) / 256;
    fill_wprep_k<<<nbE + nbW, 256, 0, stream>>>(srcv, dstv, E, offs, cur, csr, nbE,
                                                W1, aS1, aD1, W2, aS2, aD2,
                                                b1hi, b1lo, b2hi, b2lo);

    int nstrip = (N + 15) / 16;
    int nbG1 = (nstrip + 3) / 4;
    gemm1_mfma_k<<<nbG1, 256, 0, stream>>>(x, (const bf16x8*)b1hi, (const bf16x8*)b1lo,
                                           h1b, as1, ad1, N);

    int nbA = (N * 64 + 255) / 256;
    agg4_k<<<nbA, 256, 0, stream>>>((const ushort4*)h1b, (const float4*)as1, (const float4*)ad1,
                                    offs, csr, b1, h1e, N);

    gemm2_mfma_k<<<nbG1, 256, 0, stream>>>(h1e, (const bf16x8*)b2hi, (const bf16x8*)b2lo,
                                           h2b, as2, ad2, N);

    agg1_k<<<nbA, 256, 0, stream>>>(h2b, as2, ad2, offs, csr, b2, h2a, N);

    int nbGth = (E * 32 + 255) / 256;
    gather_k<<<nbGth, 256, 0, stream>>>((const ushort4*)h2a, srcv, dstv, (nfloat4*)out, E);
}